// Round 8
// baseline (90.224 us; speedup 1.0000x reference)
//
#include <hip/hip_runtime.h>
#include <hip/hip_bf16.h>
#include <math.h>

// Problem constants (match reference)
#define BB      8
#define C_CH    128
#define HH      256
#define WW      256
#define N_POS   2048
#define N_NEG   8192
#define N_ROWS  (N_POS + N_NEG)     // 10240
#define EPS_N   1e-6f

// sim tiling: block = 4 waves as 2x2, each wave 64x64 output, K=128 in 4 steps
#define NIB     (N_POS / 128)       // 16
#define NJB     (N_ROWS / 128)      // 80
#define NJSLAB      (N_ROWS / 64)   // 160 j-slabs of 64 cols (per-wave extent)
#define NJSLAB_POS  (N_POS / 64)    // 32

typedef __attribute__((ext_vector_type(8))) short bf16x8;   // 8 bf16 = 4 VGPR
typedef __attribute__((ext_vector_type(4))) float f32x4;    // MFMA C/D

// Workspace layout:
//   hi:      [N_ROWS][128] bf16   @ 0              (2.62 MB)
//   lo:      [N_ROWS][128] bf16   @ 2.62 MB        (2.62 MB)
//   partial: [NJSLAB][N_POS] f32                   (1.31 MB)
//   term:    [N_POS] f32                           (8 KB)

// ---------------------------------------------------------------------------
// Kernel 1: gather + L2-normalize + split to bf16 hi/lo.
// 2 rows per wave; all 4 scattered loads issued before either reduction so the
// wave keeps 4 lines in flight (Little's law: 20 waves/CU x 4 = 80 in-flight
// vs 32 x 2 = 64 for 1 row/wave). Lane l owns channels l and l+64.
__global__ __launch_bounds__(256) void gather_norm_kernel(
    const float* __restrict__ seg,
    const int* __restrict__ pb, const int* __restrict__ ph, const int* __restrict__ pw,
    const int* __restrict__ nb, const int* __restrict__ nh, const int* __restrict__ nw,
    __hip_bfloat16* __restrict__ hi, __hip_bfloat16* __restrict__ lo)
{
    const int wave = threadIdx.x >> 6;
    const int lane = threadIdx.x & 63;
    const int row0 = (blockIdx.x * 4 + wave) * 2;      // rows row0, row0+1

    int b0, h0, w0, b1, h1, w1;
    {
        const int r = row0;
        if (r < N_POS) { b0 = pb[r]; h0 = ph[r]; w0 = pw[r]; }
        else { const int q = r - N_POS; b0 = nb[q]; h0 = nh[q]; w0 = nw[q]; }
    }
    {
        const int r = row0 + 1;
        if (r < N_POS) { b1 = pb[r]; h1 = ph[r]; w1 = pw[r]; }
        else { const int q = r - N_POS; b1 = nb[q]; h1 = nh[q]; w1 = nw[q]; }
    }

    const size_t cs = (size_t)HH * WW;
    const size_t base0 = (size_t)b0 * C_CH * cs + (size_t)h0 * WW + (size_t)w0;
    const size_t base1 = (size_t)b1 * C_CH * cs + (size_t)h1 * WW + (size_t)w1;

    // Issue all four scattered loads up front.
    const float a0 = seg[base0 + (size_t)lane * cs];
    const float a1 = seg[base0 + (size_t)(lane + 64) * cs];
    const float c0 = seg[base1 + (size_t)lane * cs];
    const float c1 = seg[base1 + (size_t)(lane + 64) * cs];

    float sa = a0 * a0 + a1 * a1;
    float sc = c0 * c0 + c1 * c1;
#pragma unroll
    for (int m = 1; m < 64; m <<= 1) {
        sa += __shfl_xor(sa, m, 64);
        sc += __shfl_xor(sc, m, 64);
    }

    const float na = fmaxf(sqrtf(sa), EPS_N);
    const float nc = fmaxf(sqrtf(sc), EPS_N);
    const float u0 = a0 / na, u1 = a1 / na;
    const float v0 = c0 / nc, v1 = c1 / nc;

    const __hip_bfloat16 hu0 = __float2bfloat16(u0);
    const __hip_bfloat16 hu1 = __float2bfloat16(u1);
    const __hip_bfloat16 hv0 = __float2bfloat16(v0);
    const __hip_bfloat16 hv1 = __float2bfloat16(v1);
    const __hip_bfloat16 lu0 = __float2bfloat16(u0 - __bfloat162float(hu0));
    const __hip_bfloat16 lu1 = __float2bfloat16(u1 - __bfloat162float(hu1));
    const __hip_bfloat16 lv0 = __float2bfloat16(v0 - __bfloat162float(hv0));
    const __hip_bfloat16 lv1 = __float2bfloat16(v1 - __bfloat162float(hv1));

    const size_t o0 = (size_t)row0 * C_CH + lane;
    const size_t o1 = o0 + C_CH;
    hi[o0]      = hu0;  lo[o0]      = lu0;
    hi[o0 + 64] = hu1;  lo[o0 + 64] = lu1;
    hi[o1]      = hv0;  lo[o1]      = lv0;
    hi[o1 + 64] = hv1;  lo[o1 + 64] = lv1;
}

// ---------------------------------------------------------------------------
// Kernel 2: C[i][j] = dot(x_i, x_j) via 3-term split-bf16 MFMA
// (hi*hi + hi*lo + lo*hi; missing lo*lo <= 2^-18 relative).
// No LDS: fragments load straight from global (L2/L3-resident, 5.2 MB set).
// Epilogue: __expf (native v_exp_f32) + per-row sum over the wave's 64 cols;
// one write per (jslab,row) => deterministic.
__global__ __launch_bounds__(256, 2) void sim_mfma_kernel(
    const __hip_bfloat16* __restrict__ hi_, const __hip_bfloat16* __restrict__ lo_,
    float* __restrict__ partial)
{
    const ushort* __restrict__ hi = (const ushort*)hi_;
    const ushort* __restrict__ lo = (const ushort*)lo_;

    const int bid = blockIdx.x;
    const int ib  = bid / NJB;          // 0..15
    const int jb  = bid % NJB;          // 0..79  (ids sharing jb are == mod 8 -> same XCD)
    const int t    = threadIdx.x;
    const int wave = t >> 6;
    const int lane = t & 63;
    const int wy = wave >> 1;           // i-half
    const int wx = wave & 1;            // j-half

    const int iw0 = ib * 128 + wy * 64;
    const int jw0 = jb * 128 + wx * 64;

    const int lr = lane & 15;           // row/col within 16x16 tile
    const int lk = lane >> 4;           // k-chunk (8 bf16)

    f32x4 acc[4][4];
#pragma unroll
    for (int m = 0; m < 4; ++m)
#pragma unroll
        for (int n = 0; n < 4; ++n) acc[m][n] = (f32x4){0.f, 0.f, 0.f, 0.f};

#pragma unroll
    for (int ks = 0; ks < 4; ++ks) {
        const int koff = ks * 32 + lk * 8;

        bf16x8 ah[4], al[4];
#pragma unroll
        for (int m = 0; m < 4; ++m) {
            const size_t ra = (size_t)(iw0 + m * 16 + lr) * C_CH + koff;
            ah[m] = *(const bf16x8*)&hi[ra];
            al[m] = *(const bf16x8*)&lo[ra];
        }
#pragma unroll
        for (int n = 0; n < 4; ++n) {
            const size_t rb = (size_t)(jw0 + n * 16 + lr) * C_CH + koff;
            const bf16x8 bh = *(const bf16x8*)&hi[rb];
            const bf16x8 bl = *(const bf16x8*)&lo[rb];
#pragma unroll
            for (int m = 0; m < 4; ++m) {
                acc[m][n] = __builtin_amdgcn_mfma_f32_16x16x32_bf16(ah[m], bh, acc[m][n], 0, 0, 0);
                acc[m][n] = __builtin_amdgcn_mfma_f32_16x16x32_bf16(ah[m], bl, acc[m][n], 0, 0, 0);
                acc[m][n] = __builtin_amdgcn_mfma_f32_16x16x32_bf16(al[m], bh, acc[m][n], 0, 0, 0);
            }
        }
    }

    // Epilogue. C/D layout: value r of lane l = C[iw0+m*16+(l>>4)*4+r][jw0+n*16+(l&15)]
    const int jslab = jw0 >> 6;         // 0..159
#pragma unroll
    for (int m = 0; m < 4; ++m) {
        float s0 = 0.f, s1 = 0.f, s2 = 0.f, s3 = 0.f;
#pragma unroll
        for (int n = 0; n < 4; ++n) {
            s0 += __expf(acc[m][n][0]);
            s1 += __expf(acc[m][n][1]);
            s2 += __expf(acc[m][n][2]);
            s3 += __expf(acc[m][n][3]);
        }
        float s[4] = {s0, s1, s2, s3};
#pragma unroll
        for (int r = 0; r < 4; ++r) {
            float v = s[r];
            v += __shfl_xor(v, 1, 64);
            v += __shfl_xor(v, 2, 64);
            v += __shfl_xor(v, 4, 64);
            v += __shfl_xor(v, 8, 64);
            if (lr == 0) {
                const int row = iw0 + m * 16 + lk * 4 + r;
                partial[(size_t)jslab * N_POS + row] = v;
            }
        }
    }
}

// ---------------------------------------------------------------------------
// Kernel 3a: per-row reduction over the 160 j-slab partials (coalesced).
__global__ __launch_bounds__(256) void rowred_kernel(
    const float* __restrict__ partial, float* __restrict__ term)
{
    const int row = blockIdx.x * 256 + threadIdx.x;
    float P = 0.f, Nv = 0.f;
    for (int s = 0; s < NJSLAB_POS; ++s)      P  += partial[(size_t)s * N_POS + row];
    for (int s = NJSLAB_POS; s < NJSLAB; ++s) Nv += partial[(size_t)s * N_POS + row];
    const float p = P - 2.71828182845904523536f;   // remove self-sim exp(1)
    term[row] = logf(p) - logf(p + Nv);
}

// Kernel 3b: single block => deterministic final mean.
__global__ __launch_bounds__(256) void final_kernel(
    const float* __restrict__ term, float* __restrict__ out)
{
    const int t = threadIdx.x;
    float local = 0.f;
    for (int i = t; i < N_POS; i += 256) local += term[i];

    __shared__ float red[256];
    red[t] = local;
    __syncthreads();
    for (int s = 128; s > 0; s >>= 1) {
        if (t < s) red[t] += red[t + s];
        __syncthreads();
    }
    if (t == 0) out[0] = -red[0] / (float)N_POS;
}

// ---------------------------------------------------------------------------
extern "C" void kernel_launch(void* const* d_in, const int* in_sizes, int n_in,
                              void* d_out, int out_size, void* d_ws, size_t ws_size,
                              hipStream_t stream)
{
    const float* seg = (const float*)d_in[0];
    const int* pb = (const int*)d_in[1];
    const int* ph = (const int*)d_in[2];
    const int* pw = (const int*)d_in[3];
    const int* nb = (const int*)d_in[4];
    const int* nh = (const int*)d_in[5];
    const int* nw = (const int*)d_in[6];
    float* out = (float*)d_out;

    __hip_bfloat16* hi = (__hip_bfloat16*)d_ws;
    __hip_bfloat16* lo = hi + (size_t)N_ROWS * C_CH;
    float* partial = (float*)(lo + (size_t)N_ROWS * C_CH);
    float* term    = partial + (size_t)NJSLAB * N_POS;

    // 8 rows per block (2 per wave)
    gather_norm_kernel<<<dim3(N_ROWS / 8), dim3(256), 0, stream>>>(
        seg, pb, ph, pw, nb, nh, nw, hi, lo);

    sim_mfma_kernel<<<dim3(NIB * NJB), dim3(256), 0, stream>>>(hi, lo, partial);

    rowred_kernel<<<dim3(N_POS / 256), dim3(256), 0, stream>>>(partial, term);
    final_kernel<<<dim3(1), dim3(256), 0, stream>>>(term, out);
}